// Round 4
// baseline (314.391 us; speedup 1.0000x reference)
//
#include <hip/hip_runtime.h>
#include <math.h>

#define CH 4096        // edges per partition block
#define NBUK_MAX 256   // max buckets (N <= 131072)
#define MAXB 12288     // max edges per bucket staged in LDS (48 KB)
#define SRC_BITS 17    // N < 131072 fits in 17 bits

typedef short bf16x8 __attribute__((ext_vector_type(8)));
typedef float f32x4 __attribute__((ext_vector_type(4)));
typedef float f32x2 __attribute__((ext_vector_type(2)));

// bf16 <-> f32 helpers (RNE pack; exact unpack)
__device__ __forceinline__ unsigned short f2bf(float f) {
    union { float f; unsigned int u; } v; v.f = f;
    unsigned int r = (v.u + 0x7FFFu + ((v.u >> 16) & 1u)) >> 16;
    return (unsigned short)r;
}
__device__ __forceinline__ float bf2f(unsigned short u) {
    union { unsigned int u; float f; } v; v.u = ((unsigned int)u) << 16;
    return v.f;
}
// unpack packed pair (low ushort = even feature, high = odd)
__device__ __forceinline__ float bflo(unsigned int u) {
    union { unsigned int u; float f; } v; v.u = u << 16;
    return v.f;
}
__device__ __forceinline__ float bfhi(unsigned int u) {
    union { unsigned int u; float f; } v; v.u = u & 0xFFFF0000u;
    return v.f;
}

// ---------------- P1a: per-block bucket histograms (dst + src, LDS only) ----------------
// NOTE (round-2 lesson): do NOT replace the src side with global atomicAdd(&deg[src],1).
// Random-address global atomics write through at 32 B/op (52 MB WRITE_SIZE) and made
// this kernel 68 us. LDS histograms + partition is ~5x cheaper.
__global__ __launch_bounds__(256) void p1a_kernel(const int* __restrict__ src, const int* __restrict__ dst,
                                                  int* __restrict__ mat, int E, int B1, int nbuk) {
    __shared__ int hd[NBUK_MAX], hs[NBUK_MAX];
    const int t = threadIdx.x;
    if (t < nbuk) { hd[t] = 0; hs[t] = 0; }
    __syncthreads();
    const int base = blockIdx.x * CH;
    const int cnt = min(CH, E - base);
    for (int k = t; k < cnt; k += 256) {
        int d = dst[base + k];
        int s = src[base + k];
        atomicAdd(&hd[d >> 9], 1);
        atomicAdd(&hs[s >> 9], 1);
    }
    __syncthreads();
    if (t < nbuk) {
        mat[t * B1 + blockIdx.x] = hd[t];
        mat[(nbuk + t) * B1 + blockIdx.x] = hs[t];
    }
}

// ---------------- 3-phase exclusive scan ----------------
__global__ __launch_bounds__(256) void scan1_kernel(const int* __restrict__ cnt,
                                                    int* __restrict__ seg,
                                                    int* __restrict__ bsums, int N) {
    __shared__ int tsum[256];
    const int t = threadIdx.x;
    const int base = blockIdx.x * 1024 + t * 4;
    int v0 = (base + 0 < N) ? cnt[base + 0] : 0;
    int v1 = (base + 1 < N) ? cnt[base + 1] : 0;
    int v2 = (base + 2 < N) ? cnt[base + 2] : 0;
    int v3 = (base + 3 < N) ? cnt[base + 3] : 0;
    tsum[t] = v0 + v1 + v2 + v3;
    __syncthreads();
    for (int off = 1; off < 256; off <<= 1) {
        int x = (t >= off) ? tsum[t - off] : 0;
        __syncthreads();
        if (t >= off) tsum[t] += x;
        __syncthreads();
    }
    int run = (t > 0) ? tsum[t - 1] : 0;
    if (base + 0 < N) seg[base + 0] = run; run += v0;
    if (base + 1 < N) seg[base + 1] = run; run += v1;
    if (base + 2 < N) seg[base + 2] = run; run += v2;
    if (base + 3 < N) seg[base + 3] = run;
    if (t == 255) bsums[blockIdx.x] = tsum[255];
}

__global__ void scan2_kernel(int* __restrict__ bsums, int* __restrict__ seg, int N, int G) {
    __shared__ int s[256];
    int t = threadIdx.x;
    if (t < G) s[t] = bsums[t];
    __syncthreads();
    if (t == 0) {
        int run = 0;
        for (int i = 0; i < G; ++i) { int v = s[i]; s[i] = run; run += v; }
        seg[N] = run;
    }
    __syncthreads();
    if (t < G) bsums[t] = s[t];
}

__global__ __launch_bounds__(256) void scan3_kernel(int* __restrict__ seg,
                                                    const int* __restrict__ bsums, int N) {
    int add = bsums[blockIdx.x];
    int base = blockIdx.x * 1024 + threadIdx.x * 4;
#pragma unroll
    for (int i = 0; i < 4; ++i) {
        int idx = base + i;
        if (idx < N) seg[idx] += add;
    }
}

// ---------------- P1c: LDS-staged partition scatter (both sides) ----------------
// histograms are NOT recomputed: p1a already wrote them to mat.
__global__ __launch_bounds__(256) void p1c_kernel(const int* __restrict__ src, const int* __restrict__ dst,
                                                  const int* __restrict__ mat,
                                                  const int* __restrict__ scan,
                                                  int* __restrict__ pedge,
                                                  int E, int B1, int nbuk) {
    __shared__ int hd[NBUK_MAX], hs[NBUK_MAX];
    __shared__ int curD[NBUK_MAX], curS[NBUK_MAX];
    __shared__ int baseD[NBUK_MAX], baseS[NBUK_MAX];
    __shared__ int stD[CH];
    __shared__ int stS[CH];
    const int t = threadIdx.x;
    if (t < nbuk) {
        hd[t] = mat[t * B1 + blockIdx.x];
        hs[t] = mat[(nbuk + t) * B1 + blockIdx.x];
    }
    const int base = blockIdx.x * CH;
    const int cnt = min(CH, E - base);
    int dl[CH / 256], sl[CH / 256];
#pragma unroll
    for (int k = 0; k < CH / 256; ++k) {
        int i = t + k * 256;
        if (i < cnt) {
            dl[k] = dst[base + i];
            sl[k] = src[base + i];
        }
    }
    __syncthreads();
    for (int off = 1; off < nbuk; off <<= 1) {
        int v0 = (t >= off && t < nbuk) ? hd[t - off] : 0;
        int w0 = (t >= off && t < nbuk) ? hs[t - off] : 0;
        __syncthreads();
        if (t < nbuk) { hd[t] += v0; hs[t] += w0; }
        __syncthreads();
    }
    if (t < nbuk) {
        int excD = t ? hd[t - 1] : 0;
        int excS = t ? hs[t - 1] : 0;
        curD[t] = excD;
        curS[t] = excS;
        baseD[t] = scan[t * B1 + blockIdx.x] - excD;
        baseS[t] = scan[(nbuk + t) * B1 + blockIdx.x] - excS;
    }
    __syncthreads();
#pragma unroll
    for (int k = 0; k < CH / 256; ++k) {
        int i = t + k * 256;
        if (i < cnt) {
            int j = dl[k] >> 9;
            int p = atomicAdd(&curD[j], 1);
            stD[p] = ((dl[k] & 511) << SRC_BITS) | sl[k];
            int jq = sl[k] >> 9;
            int q = atomicAdd(&curS[jq], 1);
            stS[q] = sl[k];
        }
    }
    __syncthreads();
    for (int i = t; i < cnt; i += 256) {
        int lo = 0, hi = nbuk - 1;
        while (lo < hi) { int mid = (lo + hi) >> 1; if (hd[mid] > i) hi = mid; else lo = mid + 1; }
        pedge[baseD[lo] + i] = stD[i];
        int lo2 = 0, hi2 = nbuk - 1;
        while (lo2 < hi2) { int mid = (lo2 + hi2) >> 1; if (hs[mid] > i) hi2 = mid; else lo2 = mid + 1; }
        pedge[baseS[lo2] + i] = stS[i];
    }
}

// ---------------- P2+S2 merged: per-bucket sort / histograms ----------------
// blocks [0, nbuk)       : P2 role — local sort -> esrc, seg, norm_dst
// blocks [nbuk, 2*nbuk)  : S2 role — src histogram -> norm_src
__global__ __launch_bounds__(512) void p2s2_kernel(const int* __restrict__ pedge,
                                                   const int* __restrict__ scan,
                                                   int* __restrict__ esrc, int* __restrict__ seg,
                                                   float* __restrict__ norm_dst,
                                                   float* __restrict__ norm_src,
                                                   int N, int E, int B1, int nbuk) {
    __shared__ int h[512];
    __shared__ int cur[512];
    __shared__ int stage[MAXB];
    const int t = threadIdx.x;
    const int b0 = blockIdx.x;
    if (b0 >= nbuk) {
        // ---- S2 role ----
        const int b = b0 - nbuk;
        h[t] = 0;
        __syncthreads();
        const int sb0 = scan[(nbuk + b) * B1];
        const int sb1 = scan[(nbuk + b + 1) * B1];
        for (int i = sb0 + t; i < sb1; i += 512) atomicAdd(&h[pedge[i] & 511], 1);
        __syncthreads();
        int n = (b << 9) + t;
        if (n < N) norm_src[n] = rsqrtf(fmaxf((float)h[t], 1.0f));
        return;
    }
    // ---- P2 role ----
    const int b = b0;
    h[t] = 0;
    __syncthreads();
    const int bb0 = scan[b * B1];
    const int bb1 = scan[(b + 1) * B1];
    for (int i = bb0 + t; i < bb1; i += 512) atomicAdd(&h[(pedge[i] >> SRC_BITS) & 511], 1);
    __syncthreads();
    for (int off = 1; off < 512; off <<= 1) {
        int v = (t >= off) ? h[t - off] : 0;
        __syncthreads();
        h[t] += v;
        __syncthreads();
    }
    {
        int exc = t ? h[t - 1] : 0;
        cur[t] = exc;
        int n = (b << 9) + t;
        if (n < N) {
            seg[n] = bb0 + exc;
            norm_dst[n] = rsqrtf(fmaxf((float)(h[t] - exc), 1.0f));
        }
        if (b == 0 && t == 0) seg[N] = E;
    }
    __syncthreads();
    const int cnt = bb1 - bb0;
    for (int i = bb0 + t; i < bb1; i += 512) {
        int v = pedge[i];
        int j = (v >> SRC_BITS) & 511;
        int p = atomicAdd(&cur[j], 1);
        int s = v & ((1 << SRC_BITS) - 1);
        if (p < MAXB) stage[p] = s; else esrc[bb0 + p] = s;
    }
    __syncthreads();
    for (int i = t; i < cnt && i < MAXB; i += 512) esrc[bb0 + i] = stage[i];
}

// ---------------- X(bf16) = (H @ W) * norm_row  — MFMA split-bf16 ----------------
// X is stored CHUNK-MAJOR: 8 chunks x (N+1) nodes x 8 features (16 B).
// Chunk c holds features [c*8, c*8+8) of every node in a contiguous 1.6 MB
// region -> segsum blocks with XCD-affinity c keep their chunk L2-resident.
// Row N (one past the real nodes) is all-zero in every chunk: segsum's
// branchless tail redirects out-of-range edge slots to it.
template<int K>
__global__ __launch_bounds__(256) void gemm_norm(const float* __restrict__ H,
                                                 const float* __restrict__ W,
                                                 const float* __restrict__ norm,
                                                 unsigned short* __restrict__ X, int N) {
    constexpr int KP = K + 8;  // padded stride (halves)
    __shared__ __align__(16) unsigned short sHi[64 * KP];
    __shared__ __align__(16) unsigned short sLo[64 * KP];
    const int tid = threadIdx.x;

    // stage W (row-major [K][64]) transposed, split hi/lo
    for (int idx = tid; idx < K * 64; idx += 256) {
        int k = idx >> 6;
        int c = idx & 63;
        float v = W[idx];
        unsigned short hi = f2bf(v);
        sHi[c * KP + k] = hi;
        sLo[c * KP + k] = f2bf(v - bf2f(hi));
    }
    __syncthreads();

    const int w = tid >> 6;
    const int lane = tid & 63;
    const int quad = lane >> 4;
    const int l16 = lane & 15;
    const int n0 = blockIdx.x * 64;
    const int arow = n0 + w * 16 + l16;
    const int arow_c = (arow < N) ? arow : (N - 1);
    const float* Hrow = H + (size_t)arow_c * K + quad * 8;

    f32x4 acc[4];
#pragma unroll
    for (int t = 0; t < 4; ++t) acc[t] = (f32x4){0.0f, 0.0f, 0.0f, 0.0f};

    float4 p0 = *(const float4*)(Hrow + 0);
    float4 p1 = *(const float4*)(Hrow + 4);

#pragma unroll
    for (int kc = 0; kc < K / 32; ++kc) {
        const float v[8] = {p0.x, p0.y, p0.z, p0.w, p1.x, p1.y, p1.z, p1.w};
        bf16x8 aHi, aLo;
#pragma unroll
        for (int j = 0; j < 8; ++j) {
            unsigned short hi = f2bf(v[j]);
            aHi[j] = (short)hi;
            aLo[j] = (short)f2bf(v[j] - bf2f(hi));
        }
        if (kc + 1 < K / 32) {
            p0 = *(const float4*)(Hrow + (kc + 1) * 32 + 0);
            p1 = *(const float4*)(Hrow + (kc + 1) * 32 + 4);
        }
        const int kbase = kc * 32 + quad * 8;
#pragma unroll
        for (int t = 0; t < 4; ++t) {
            const int col = t * 16 + l16;
            const bf16x8 bHi = *(const bf16x8*)&sHi[col * KP + kbase];
            const bf16x8 bLo = *(const bf16x8*)&sLo[col * KP + kbase];
            acc[t] = __builtin_amdgcn_mfma_f32_16x16x32_bf16(aLo, bHi, acc[t], 0, 0, 0);
            acc[t] = __builtin_amdgcn_mfma_f32_16x16x32_bf16(aHi, bLo, acc[t], 0, 0, 0);
            acc[t] = __builtin_amdgcn_mfma_f32_16x16x32_bf16(aHi, bHi, acc[t], 0, 0, 0);
        }
    }

    const size_t CS = 8 * (size_t)(N + 1);   // chunk stride in ushorts
    const int sub = l16 & 7;                 // feature within chunk
#pragma unroll
    for (int r = 0; r < 4; ++r) {
        const int node = n0 + w * 16 + quad * 4 + r;
        if (node < N) {
            const float s = norm[node];
#pragma unroll
            for (int t = 0; t < 4; ++t) {
                const int chunk = t * 2 + (l16 >> 3);
                X[chunk * CS + (size_t)node * 8 + sub] = f2bf(acc[t][r] * s);
            }
        } else if (node == N) {
            // zero row for segsum's branchless tail redirect
#pragma unroll
            for (int t = 0; t < 4; ++t) {
                const int chunk = t * 2 + (l16 >> 3);
                X[chunk * CS + (size_t)node * 8 + sub] = 0;
            }
        }
    }
}

// ---------------- segment sum over CSR (chunk-major bf16 X) + fused epilogue ----------------
// Grid = (node groups) x 8 chunks; c = blockIdx.x % 8 pins chunk c to XCD c
// (round-robin dispatch) -> each XCD's gathers stay inside a 1.6 MB L2-resident
// region. Per wave: 8 nodes x 8 edge-slots; each slot-lane gathers uint4
// (8 bf16 features), 2-deep; 3-stage reduce-scatter leaves each lane owning
// one feature -> coalesced 32 B store per node.
template<bool ELU>
__global__ __launch_bounds__(256) void segsum_kernel(const unsigned short* __restrict__ X,
                                                     const int* __restrict__ esrc,
                                                     const int* __restrict__ seg,
                                                     const float* __restrict__ norm_dst,
                                                     const float* __restrict__ bias,
                                                     float* __restrict__ out, int N) {
    const int c = blockIdx.x & 7;
    const int g = blockIdx.x >> 3;
    const int lane = threadIdx.x & 63;
    const int slot = lane & 7;
    const int node = g * 32 + ((threadIdx.x >> 6) << 3) + (lane >> 3);
    const int frev = ((slot & 1) << 2) | (slot & 2) | (slot >> 2);
    const char* Xc = (const char*)X + (((size_t)c * (size_t)(N + 1)) << 4);
    const bool act = node < N;
    const int s0 = act ? seg[node] : 0;
    const int s1 = act ? seg[node + 1] : 0;
    f32x2 A0 = {0.0f, 0.0f}, A1 = {0.0f, 0.0f}, A2 = {0.0f, 0.0f}, A3 = {0.0f, 0.0f};
#define ACC8(u) \
    A0 += (f32x2){bflo(u.x), bfhi(u.x)}; A1 += (f32x2){bflo(u.y), bfhi(u.y)}; \
    A2 += (f32x2){bflo(u.z), bfhi(u.z)}; A3 += (f32x2){bflo(u.w), bfhi(u.w)};
    int e = s0;
    for (; e + 16 <= s1; e += 16) {       // all 16 edges valid: no masking
        const int r0 = esrc[e + slot];
        const int r1 = esrc[e + 8 + slot];
        const uint4 u0 = *(const uint4*)(Xc + (((unsigned)r0) << 4));
        const uint4 u1 = *(const uint4*)(Xc + (((unsigned)r1) << 4));
        ACC8(u0);
        ACC8(u1);
    }
    if (e < s1) {                         // masked tail: redirect to zero row
        const int i0 = e + slot;
        const int i1 = e + 8 + slot;
        const int q0 = esrc[i0];          // over-read <=15 ints: esrc is padded
        const int q1 = esrc[i1];
        const int r0 = (i0 < s1) ? q0 : N;
        const int r1 = (i1 < s1) ? q1 : N;
        const uint4 u0 = *(const uint4*)(Xc + (((unsigned)r0) << 4));
        const uint4 u1 = *(const uint4*)(Xc + (((unsigned)r1) << 4));
        ACC8(u0);
        ACC8(u1);
    }
#undef ACC8
    // reduce-scatter across the 8 slot-lanes: 3 stages (xor 1, 2, 4)
    float a0 = A0.x, a1 = A0.y, a2 = A1.x, a3 = A1.y;
    float a4 = A2.x, a5 = A2.y, a6 = A3.x, a7 = A3.y;
    const bool q0 = (slot & 1) != 0;
    const bool q1 = (slot & 2) != 0;
    const bool q2 = (slot & 4) != 0;
    float t0, t1, t2, t3;
    {
        float sA = q0 ? a0 : a4, kA = q0 ? a4 : a0;
        float sB = q0 ? a1 : a5, kB = q0 ? a5 : a1;
        float sC = q0 ? a2 : a6, kC = q0 ? a6 : a2;
        float sD = q0 ? a3 : a7, kD = q0 ? a7 : a3;
        t0 = kA + __shfl_xor(sA, 1);
        t1 = kB + __shfl_xor(sB, 1);
        t2 = kC + __shfl_xor(sC, 1);
        t3 = kD + __shfl_xor(sD, 1);
    }
    float u0, u1;
    {
        float sA = q1 ? t0 : t2, kA = q1 ? t2 : t0;
        float sB = q1 ? t1 : t3, kB = q1 ? t3 : t1;
        u0 = kA + __shfl_xor(sA, 2);
        u1 = kB + __shfl_xor(sB, 2);
    }
    float v;
    {
        float sA = q2 ? u0 : u1, kA = q2 ? u1 : u0;
        v = kA + __shfl_xor(sA, 4);
    }
    if (act) {
        const float s = norm_dst[node];
        float r = v * s + bias[c * 8 + frev];
        if (ELU) r = r > 0.0f ? r : expm1f(r);
        out[(size_t)node * 64 + c * 8 + frev] = r;
    }
}

extern "C" void kernel_launch(void* const* d_in, const int* in_sizes, int n_in,
                              void* d_out, int out_size, void* d_ws, size_t ws_size,
                              hipStream_t stream) {
    const float* h   = (const float*)d_in[0];
    const int*   src = (const int*)d_in[1];
    const int*   dst = (const int*)d_in[2];
    const float* W1  = (const float*)d_in[3];
    const float* b1  = (const float*)d_in[4];
    const float* W2  = (const float*)d_in[5];
    const float* b2  = (const float*)d_in[6];
    float* out = (float*)d_out;

    const int N = in_sizes[0] / 128;       // 100000
    const int E = in_sizes[1];             // 1600000
    const int nbuk = (N + 511) >> 9;       // 196
    const int B1 = (E + CH - 1) / CH;      // 391
    const int M = 2 * nbuk * B1;

    int* iw = (int*)d_ws;
    int* mat   = iw;                       // M
    int* scanb = mat + M;                  // M+4
    int* bsums = scanb + M + 4;            // 256
    int* pedge = bsums + 256;              // 2E
    int* esrc  = pedge + 2 * (size_t)E;    // E (+16 pad for segsum over-read)
    int* seg   = esrc + (size_t)E + 16;    // N+1 (+pad)
    uintptr_t fp = (uintptr_t)(seg + (size_t)N + 4);
    fp = (fp + 63) & ~(uintptr_t)63;
    float* norm_src = (float*)fp;                      // N
    float* norm_dst = norm_src + (size_t)N;            // N
    float* H1       = norm_dst + (size_t)N;            // 64N floats
    unsigned short* Xb = (unsigned short*)(H1 + 64 * (size_t)N);  // 64(N+1) bf16, chunk-major

    // ---- CSR build ----
    p1a_kernel<<<B1, 256, 0, stream>>>(src, dst, mat, E, B1, nbuk);
    const int G = (M + 1023) / 1024;
    scan1_kernel<<<G, 256, 0, stream>>>(mat, scanb, bsums, M);
    scan2_kernel<<<1, 256, 0, stream>>>(bsums, scanb, M, G);
    scan3_kernel<<<G, 256, 0, stream>>>(scanb, bsums, M);
    p1c_kernel<<<B1, 256, 0, stream>>>(src, dst, mat, scanb, pedge, E, B1, nbuk);
    p2s2_kernel<<<2 * nbuk, 512, 0, stream>>>(pedge, scanb, esrc, seg, norm_dst, norm_src,
                                              N, E, B1, nbuk);

    const int segGrid = ((N + 31) / 32) * 8;   // node-groups x 8 feature chunks
    const int gemmGrid = (N + 64) / 64;        // +1 so the zero row (node==N) is always written

    // ---- layer 1 ----
    gemm_norm<128><<<gemmGrid, 256, 0, stream>>>(h, W1, norm_src, Xb, N);
    segsum_kernel<true><<<segGrid, 256, 0, stream>>>(Xb, esrc, seg, norm_dst, b1, H1, N);

    // ---- layer 2 ----
    gemm_norm<64><<<gemmGrid, 256, 0, stream>>>(H1, W2, norm_src, Xb, N);
    segsum_kernel<false><<<segGrid, 256, 0, stream>>>(Xb, esrc, seg, norm_dst, b2, out, N);
}

// Round 5
// 253.535 us; speedup vs baseline: 1.2400x; 1.2400x over previous
//
#include <hip/hip_runtime.h>
#include <math.h>

#define CH 4096        // edges per partition block
#define NBUK_MAX 256   // max buckets (N <= 131072)
#define MAXB 12288     // max edges per bucket staged in LDS (48 KB)
#define SRC_BITS 17    // N < 131072 fits in 17 bits

typedef short bf16x8 __attribute__((ext_vector_type(8)));
typedef float f32x4 __attribute__((ext_vector_type(4)));
typedef float f32x2 __attribute__((ext_vector_type(2)));

// bf16 <-> f32 helpers (RNE pack; exact unpack)
__device__ __forceinline__ unsigned short f2bf(float f) {
    union { float f; unsigned int u; } v; v.f = f;
    unsigned int r = (v.u + 0x7FFFu + ((v.u >> 16) & 1u)) >> 16;
    return (unsigned short)r;
}
__device__ __forceinline__ float bf2f(unsigned short u) {
    union { unsigned int u; float f; } v; v.u = ((unsigned int)u) << 16;
    return v.f;
}
// unpack packed pair (low ushort = even feature, high = odd)
__device__ __forceinline__ float bflo(unsigned int u) {
    union { unsigned int u; float f; } v; v.u = u << 16;
    return v.f;
}
__device__ __forceinline__ float bfhi(unsigned int u) {
    union { unsigned int u; float f; } v; v.u = u & 0xFFFF0000u;
    return v.f;
}

// ---------------- P1a: per-block bucket histograms (dst + src, LDS only) ----------------
// Round-2 lesson: NO global atomicAdd(&deg[src],1) (32 B write-through per op, 68 us).
// Round-5: wave-parity dual sub-histograms halve LDS-atomic contention.
__global__ __launch_bounds__(256) void p1a_kernel(const int* __restrict__ src, const int* __restrict__ dst,
                                                  int* __restrict__ mat, int E, int B1, int nbuk) {
    __shared__ int hd[2][NBUK_MAX], hs[2][NBUK_MAX];
    const int t = threadIdx.x;
    const int p = (t >> 6) & 1;   // wave parity
    if (t < nbuk) { hd[0][t] = 0; hd[1][t] = 0; hs[0][t] = 0; hs[1][t] = 0; }
    __syncthreads();
    const int base = blockIdx.x * CH;
    const int cnt = min(CH, E - base);
    for (int k = t; k < cnt; k += 256) {
        int d = dst[base + k];
        int s = src[base + k];
        atomicAdd(&hd[p][d >> 9], 1);
        atomicAdd(&hs[p][s >> 9], 1);
    }
    __syncthreads();
    if (t < nbuk) {
        mat[t * B1 + blockIdx.x] = hd[0][t] + hd[1][t];
        mat[(nbuk + t) * B1 + blockIdx.x] = hs[0][t] + hs[1][t];
    }
}

// ---------------- 3-phase exclusive scan ----------------
__global__ __launch_bounds__(256) void scan1_kernel(const int* __restrict__ cnt,
                                                    int* __restrict__ seg,
                                                    int* __restrict__ bsums, int N) {
    __shared__ int tsum[256];
    const int t = threadIdx.x;
    const int base = blockIdx.x * 1024 + t * 4;
    int v0 = (base + 0 < N) ? cnt[base + 0] : 0;
    int v1 = (base + 1 < N) ? cnt[base + 1] : 0;
    int v2 = (base + 2 < N) ? cnt[base + 2] : 0;
    int v3 = (base + 3 < N) ? cnt[base + 3] : 0;
    tsum[t] = v0 + v1 + v2 + v3;
    __syncthreads();
    for (int off = 1; off < 256; off <<= 1) {
        int x = (t >= off) ? tsum[t - off] : 0;
        __syncthreads();
        if (t >= off) tsum[t] += x;
        __syncthreads();
    }
    int run = (t > 0) ? tsum[t - 1] : 0;
    if (base + 0 < N) seg[base + 0] = run; run += v0;
    if (base + 1 < N) seg[base + 1] = run; run += v1;
    if (base + 2 < N) seg[base + 2] = run; run += v2;
    if (base + 3 < N) seg[base + 3] = run;
    if (t == 255) bsums[blockIdx.x] = tsum[255];
}

__global__ void scan2_kernel(int* __restrict__ bsums, int* __restrict__ seg, int N, int G) {
    __shared__ int s[256];
    int t = threadIdx.x;
    if (t < G) s[t] = bsums[t];
    __syncthreads();
    if (t == 0) {
        int run = 0;
        for (int i = 0; i < G; ++i) { int v = s[i]; s[i] = run; run += v; }
        seg[N] = run;
    }
    __syncthreads();
    if (t < G) bsums[t] = s[t];
}

__global__ __launch_bounds__(256) void scan3_kernel(int* __restrict__ seg,
                                                    const int* __restrict__ bsums, int N) {
    int add = bsums[blockIdx.x];
    int base = blockIdx.x * 1024 + threadIdx.x * 4;
#pragma unroll
    for (int i = 0; i < 4; ++i) {
        int idx = base + i;
        if (idx < N) seg[idx] += add;
    }
}

// ---------------- P1c: LDS-staged partition scatter (both sides) ----------------
// histograms are NOT recomputed: p1a already wrote them to mat.
__global__ __launch_bounds__(256) void p1c_kernel(const int* __restrict__ src, const int* __restrict__ dst,
                                                  const int* __restrict__ mat,
                                                  const int* __restrict__ scan,
                                                  int* __restrict__ pedge,
                                                  int E, int B1, int nbuk) {
    __shared__ int hd[NBUK_MAX], hs[NBUK_MAX];
    __shared__ int curD[NBUK_MAX], curS[NBUK_MAX];
    __shared__ int baseD[NBUK_MAX], baseS[NBUK_MAX];
    __shared__ int stD[CH];
    __shared__ int stS[CH];
    const int t = threadIdx.x;
    if (t < nbuk) {
        hd[t] = mat[t * B1 + blockIdx.x];
        hs[t] = mat[(nbuk + t) * B1 + blockIdx.x];
    }
    const int base = blockIdx.x * CH;
    const int cnt = min(CH, E - base);
    int dl[CH / 256], sl[CH / 256];
#pragma unroll
    for (int k = 0; k < CH / 256; ++k) {
        int i = t + k * 256;
        if (i < cnt) {
            dl[k] = dst[base + i];
            sl[k] = src[base + i];
        }
    }
    __syncthreads();
    for (int off = 1; off < nbuk; off <<= 1) {
        int v0 = (t >= off && t < nbuk) ? hd[t - off] : 0;
        int w0 = (t >= off && t < nbuk) ? hs[t - off] : 0;
        __syncthreads();
        if (t < nbuk) { hd[t] += v0; hs[t] += w0; }
        __syncthreads();
    }
    if (t < nbuk) {
        int excD = t ? hd[t - 1] : 0;
        int excS = t ? hs[t - 1] : 0;
        curD[t] = excD;
        curS[t] = excS;
        baseD[t] = scan[t * B1 + blockIdx.x] - excD;
        baseS[t] = scan[(nbuk + t) * B1 + blockIdx.x] - excS;
    }
    __syncthreads();
#pragma unroll
    for (int k = 0; k < CH / 256; ++k) {
        int i = t + k * 256;
        if (i < cnt) {
            int j = dl[k] >> 9;
            int p = atomicAdd(&curD[j], 1);
            stD[p] = ((dl[k] & 511) << SRC_BITS) | sl[k];
            int jq = sl[k] >> 9;
            int q = atomicAdd(&curS[jq], 1);
            stS[q] = sl[k];
        }
    }
    __syncthreads();
    for (int i = t; i < cnt; i += 256) {
        int lo = 0, hi = nbuk - 1;
        while (lo < hi) { int mid = (lo + hi) >> 1; if (hd[mid] > i) hi = mid; else lo = mid + 1; }
        pedge[baseD[lo] + i] = stD[i];
        int lo2 = 0, hi2 = nbuk - 1;
        while (lo2 < hi2) { int mid = (lo2 + hi2) >> 1; if (hs[mid] > i) hi2 = mid; else lo2 = mid + 1; }
        pedge[baseS[lo2] + i] = stS[i];
    }
}

// ---------------- P2+S2 merged: per-bucket sort / histograms ----------------
// blocks [0, nbuk)       : P2 role — local sort -> esrc, seg, norm_dst
// blocks [nbuk, 2*nbuk)  : S2 role — src histogram -> norm_src
__global__ __launch_bounds__(512) void p2s2_kernel(const int* __restrict__ pedge,
                                                   const int* __restrict__ scan,
                                                   int* __restrict__ esrc, int* __restrict__ seg,
                                                   float* __restrict__ norm_dst,
                                                   float* __restrict__ norm_src,
                                                   int N, int E, int B1, int nbuk) {
    __shared__ int h[512];
    __shared__ int cur[512];
    __shared__ int stage[MAXB];
    const int t = threadIdx.x;
    const int b0 = blockIdx.x;
    if (b0 >= nbuk) {
        // ---- S2 role ----
        const int b = b0 - nbuk;
        h[t] = 0;
        __syncthreads();
        const int sb0 = scan[(nbuk + b) * B1];
        const int sb1 = scan[(nbuk + b + 1) * B1];
        for (int i = sb0 + t; i < sb1; i += 512) atomicAdd(&h[pedge[i] & 511], 1);
        __syncthreads();
        int n = (b << 9) + t;
        if (n < N) norm_src[n] = rsqrtf(fmaxf((float)h[t], 1.0f));
        return;
    }
    // ---- P2 role ----
    const int b = b0;
    h[t] = 0;
    __syncthreads();
    const int bb0 = scan[b * B1];
    const int bb1 = scan[(b + 1) * B1];
    for (int i = bb0 + t; i < bb1; i += 512) atomicAdd(&h[(pedge[i] >> SRC_BITS) & 511], 1);
    __syncthreads();
    for (int off = 1; off < 512; off <<= 1) {
        int v = (t >= off) ? h[t - off] : 0;
        __syncthreads();
        h[t] += v;
        __syncthreads();
    }
    {
        int exc = t ? h[t - 1] : 0;
        cur[t] = exc;
        int n = (b << 9) + t;
        if (n < N) {
            seg[n] = bb0 + exc;
            norm_dst[n] = rsqrtf(fmaxf((float)(h[t] - exc), 1.0f));
        }
        if (b == 0 && t == 0) seg[N] = E;
    }
    __syncthreads();
    const int cnt = bb1 - bb0;
    for (int i = bb0 + t; i < bb1; i += 512) {
        int v = pedge[i];
        int j = (v >> SRC_BITS) & 511;
        int p = atomicAdd(&cur[j], 1);
        int s = v & ((1 << SRC_BITS) - 1);
        if (p < MAXB) stage[p] = s; else esrc[bb0 + p] = s;
    }
    __syncthreads();
    for (int i = t; i < cnt && i < MAXB; i += 512) esrc[bb0 + i] = stage[i];
}

// ---------------- X(bf16) = (H @ W) * norm_row  — MFMA split-bf16 ----------------
// Row-major X (128 B/row = one cache line: 8 feature-lanes coalesce to ONE line
// per edge in segsum — round-4 lesson: chunk-split layouts 8x the request count).
// Row N (one past the real nodes) is all-zero: segsum's masked slots redirect to it.
template<int K>
__global__ __launch_bounds__(256) void gemm_norm(const float* __restrict__ H,
                                                 const float* __restrict__ W,
                                                 const float* __restrict__ norm,
                                                 unsigned short* __restrict__ X, int N) {
    constexpr int KP = K + 8;  // padded stride (halves)
    __shared__ __align__(16) unsigned short sHi[64 * KP];
    __shared__ __align__(16) unsigned short sLo[64 * KP];
    const int tid = threadIdx.x;

    // stage W (row-major [K][64]) transposed, split hi/lo
    for (int idx = tid; idx < K * 64; idx += 256) {
        int k = idx >> 6;
        int c = idx & 63;
        float v = W[idx];
        unsigned short hi = f2bf(v);
        sHi[c * KP + k] = hi;
        sLo[c * KP + k] = f2bf(v - bf2f(hi));
    }
    __syncthreads();

    const int w = tid >> 6;
    const int lane = tid & 63;
    const int quad = lane >> 4;
    const int l16 = lane & 15;
    const int n0 = blockIdx.x * 64;
    const int arow = n0 + w * 16 + l16;
    const int arow_c = (arow < N) ? arow : (N - 1);
    const float* Hrow = H + (size_t)arow_c * K + quad * 8;

    f32x4 acc[4];
#pragma unroll
    for (int t = 0; t < 4; ++t) acc[t] = (f32x4){0.0f, 0.0f, 0.0f, 0.0f};

    float4 p0 = *(const float4*)(Hrow + 0);
    float4 p1 = *(const float4*)(Hrow + 4);

#pragma unroll
    for (int kc = 0; kc < K / 32; ++kc) {
        const float v[8] = {p0.x, p0.y, p0.z, p0.w, p1.x, p1.y, p1.z, p1.w};
        bf16x8 aHi, aLo;
#pragma unroll
        for (int j = 0; j < 8; ++j) {
            unsigned short hi = f2bf(v[j]);
            aHi[j] = (short)hi;
            aLo[j] = (short)f2bf(v[j] - bf2f(hi));
        }
        if (kc + 1 < K / 32) {
            p0 = *(const float4*)(Hrow + (kc + 1) * 32 + 0);
            p1 = *(const float4*)(Hrow + (kc + 1) * 32 + 4);
        }
        const int kbase = kc * 32 + quad * 8;
#pragma unroll
        for (int t = 0; t < 4; ++t) {
            const int col = t * 16 + l16;
            const bf16x8 bHi = *(const bf16x8*)&sHi[col * KP + kbase];
            const bf16x8 bLo = *(const bf16x8*)&sLo[col * KP + kbase];
            acc[t] = __builtin_amdgcn_mfma_f32_16x16x32_bf16(aLo, bHi, acc[t], 0, 0, 0);
            acc[t] = __builtin_amdgcn_mfma_f32_16x16x32_bf16(aHi, bLo, acc[t], 0, 0, 0);
            acc[t] = __builtin_amdgcn_mfma_f32_16x16x32_bf16(aHi, bHi, acc[t], 0, 0, 0);
        }
    }

#pragma unroll
    for (int r = 0; r < 4; ++r) {
        const int node = n0 + w * 16 + quad * 4 + r;
        if (node < N) {
            const float s = norm[node];
#pragma unroll
            for (int t = 0; t < 4; ++t) {
                X[(size_t)node * 64 + t * 16 + l16] = f2bf(acc[t][r] * s);
            }
        } else if (node == N) {
            // zero row for segsum's masked-slot redirect
#pragma unroll
            for (int t = 0; t < 4; ++t) {
                X[(size_t)node * 64 + t * 16 + l16] = 0;
            }
        }
    }
}

// ---------------- segment sum over CSR (bf16 X rows) + fused epilogue ----------------
// 1 node per wave (zero divergence). FLAT-32: deg ~ Poisson(16) so P(deg>32)~1e-4;
// a single pass issues 4 esrc loads + 4 masked-redirect uint4 gathers — 8 memory
// ops in flight simultaneously (2x round-3's MLP), no main/tail split. Out-of-range
// slots gather the L1-hot zero row X[N]. Rare deg>32 loops additional 32-edge passes.
// Epilogue: 3-stage reduce-scatter -> each lane owns one feature -> coalesced store.
template<bool ELU>
__global__ __launch_bounds__(256) void segsum_kernel(const unsigned short* __restrict__ X,
                                                     const int* __restrict__ esrc,
                                                     const int* __restrict__ seg,
                                                     const float* __restrict__ norm_dst,
                                                     const float* __restrict__ bias,
                                                     float* __restrict__ out, int N) {
    const int node = __builtin_amdgcn_readfirstlane(blockIdx.x * 4 + (threadIdx.x >> 6));
    if (node >= N) return;
    const int lane = threadIdx.x & 63;
    const int eh = lane >> 3;          // edge slot 0..7
    const int fl = lane & 7;           // feature group (8 bf16 = 16 B)
    const unsigned flo = (unsigned)fl << 4;
    // feature this lane will own after reduce-scatter (bit-reversed eh)
    const int fown = fl * 8 + ((eh & 1) << 2) + (eh & 2) + (eh >> 2);
    const float bv = bias[fown];
    const int s0 = seg[node];
    const int s1 = seg[node + 1];
    const char* Xb = (const char*)X;
    f32x2 A0 = {0.0f, 0.0f}, A1 = {0.0f, 0.0f}, A2 = {0.0f, 0.0f}, A3 = {0.0f, 0.0f};
#define ACC8(u) \
    A0 += (f32x2){bflo(u.x), bfhi(u.x)}; A1 += (f32x2){bflo(u.y), bfhi(u.y)}; \
    A2 += (f32x2){bflo(u.z), bfhi(u.z)}; A3 += (f32x2){bflo(u.w), bfhi(u.w)};
    int e = s0;
    while (true) {
        const int i0 = e + eh;
        const int i1 = e + 8 + eh;
        const int i2 = e + 16 + eh;
        const int i3 = e + 24 + eh;
        const int q0 = esrc[i0];      // esrc padded by 40 ints: over-read is safe
        const int q1 = esrc[i1];
        const int q2 = esrc[i2];
        const int q3 = esrc[i3];
        const int r0 = (i0 < s1) ? q0 : N;
        const int r1 = (i1 < s1) ? q1 : N;
        const int r2 = (i2 < s1) ? q2 : N;
        const int r3 = (i3 < s1) ? q3 : N;
        const uint4 u0 = *(const uint4*)(Xb + ((((unsigned)r0) << 7) | flo));
        const uint4 u1 = *(const uint4*)(Xb + ((((unsigned)r1) << 7) | flo));
        const uint4 u2 = *(const uint4*)(Xb + ((((unsigned)r2) << 7) | flo));
        const uint4 u3 = *(const uint4*)(Xb + ((((unsigned)r3) << 7) | flo));
        ACC8(u0);
        ACC8(u1);
        ACC8(u2);
        ACC8(u3);
        e += 32;
        if (e >= s1) break;
    }
#undef ACC8
    // reduce-scatter across the 8 slots: 3 stages, each lane keeps a shrinking set
    float a0 = A0.x, a1 = A0.y, a2 = A1.x, a3 = A1.y;
    float a4 = A2.x, a5 = A2.y, a6 = A3.x, a7 = A3.y;
    const bool p0 = (eh & 1) != 0;
    const bool p1 = (eh & 2) != 0;
    const bool p2 = (eh & 4) != 0;
    float t0, t1, t2, t3;
    {
        float sA = p0 ? a0 : a4, kA = p0 ? a4 : a0;
        float sB = p0 ? a1 : a5, kB = p0 ? a5 : a1;
        float sC = p0 ? a2 : a6, kC = p0 ? a6 : a2;
        float sD = p0 ? a3 : a7, kD = p0 ? a7 : a3;
        t0 = kA + __shfl_xor(sA, 8);
        t1 = kB + __shfl_xor(sB, 8);
        t2 = kC + __shfl_xor(sC, 8);
        t3 = kD + __shfl_xor(sD, 8);
    }
    float u0, u1;
    {
        float sA = p1 ? t0 : t2, kA = p1 ? t2 : t0;
        float sB = p1 ? t1 : t3, kB = p1 ? t3 : t1;
        u0 = kA + __shfl_xor(sA, 16);
        u1 = kB + __shfl_xor(sB, 16);
    }
    float v;
    {
        float sA = p2 ? u0 : u1, kA = p2 ? u1 : u0;
        v = kA + __shfl_xor(sA, 32);
    }
    // epilogue: every lane handles exactly one feature
    const float s = norm_dst[node];
    float r = v * s + bv;
    if (ELU) r = r > 0.0f ? r : expm1f(r);
    out[(size_t)node * 64 + fown] = r;
}

extern "C" void kernel_launch(void* const* d_in, const int* in_sizes, int n_in,
                              void* d_out, int out_size, void* d_ws, size_t ws_size,
                              hipStream_t stream) {
    const float* h   = (const float*)d_in[0];
    const int*   src = (const int*)d_in[1];
    const int*   dst = (const int*)d_in[2];
    const float* W1  = (const float*)d_in[3];
    const float* b1  = (const float*)d_in[4];
    const float* W2  = (const float*)d_in[5];
    const float* b2  = (const float*)d_in[6];
    float* out = (float*)d_out;

    const int N = in_sizes[0] / 128;       // 100000
    const int E = in_sizes[1];             // 1600000
    const int nbuk = (N + 511) >> 9;       // 196
    const int B1 = (E + CH - 1) / CH;      // 391
    const int M = 2 * nbuk * B1;

    int* iw = (int*)d_ws;
    int* mat   = iw;                       // M
    int* scanb = mat + M;                  // M+4
    int* bsums = scanb + M + 4;            // 256
    int* pedge = bsums + 256;              // 2E
    int* esrc  = pedge + 2 * (size_t)E;    // E (+40 pad for flat-32 over-read)
    int* seg   = esrc + (size_t)E + 40;    // N+1 (+pad)
    uintptr_t fp = (uintptr_t)(seg + (size_t)N + 4);
    fp = (fp + 63) & ~(uintptr_t)63;
    float* norm_src = (float*)fp;                      // N
    float* norm_dst = norm_src + (size_t)N;            // N
    float* H1       = norm_dst + (size_t)N;            // 64N floats
    unsigned short* Xb = (unsigned short*)(H1 + 64 * (size_t)N);  // 64(N+1) bf16

    // ---- CSR build ----
    p1a_kernel<<<B1, 256, 0, stream>>>(src, dst, mat, E, B1, nbuk);
    const int G = (M + 1023) / 1024;
    scan1_kernel<<<G, 256, 0, stream>>>(mat, scanb, bsums, M);
    scan2_kernel<<<1, 256, 0, stream>>>(bsums, scanb, M, G);
    scan3_kernel<<<G, 256, 0, stream>>>(scanb, bsums, M);
    p1c_kernel<<<B1, 256, 0, stream>>>(src, dst, mat, scanb, pedge, E, B1, nbuk);
    p2s2_kernel<<<2 * nbuk, 512, 0, stream>>>(pedge, scanb, esrc, seg, norm_dst, norm_src,
                                              N, E, B1, nbuk);

    const int segGrid = (N + 3) / 4;
    const int gemmGrid = (N + 64) / 64;    // +1 so the zero row (node==N) is always written

    // ---- layer 1 ----
    gemm_norm<128><<<gemmGrid, 256, 0, stream>>>(h, W1, norm_src, Xb, N);
    segsum_kernel<true><<<segGrid, 256, 0, stream>>>(Xb, esrc, seg, norm_dst, b1, H1, N);

    // ---- layer 2 ----
    gemm_norm<64><<<gemmGrid, 256, 0, stream>>>(H1, W2, norm_src, Xb, N);
    segsum_kernel<false><<<segGrid, 256, 0, stream>>>(Xb, esrc, seg, norm_dst, b2, out, N);
}

// Round 6
// 238.688 us; speedup vs baseline: 1.3172x; 1.0622x over previous
//
#include <hip/hip_runtime.h>
#include <math.h>

#define CH 4096        // edges per partition block
#define NBUK_MAX 256   // max buckets (N <= 131072)
#define MAXB 12288     // max edges per bucket staged in LDS (48 KB)
#define SRC_BITS 17    // N < 131072 fits in 17 bits

typedef short bf16x8 __attribute__((ext_vector_type(8)));
typedef float f32x4 __attribute__((ext_vector_type(4)));
typedef float f32x2 __attribute__((ext_vector_type(2)));

// bf16 <-> f32 helpers (RNE pack; exact unpack)
__device__ __forceinline__ unsigned short f2bf(float f) {
    union { float f; unsigned int u; } v; v.f = f;
    unsigned int r = (v.u + 0x7FFFu + ((v.u >> 16) & 1u)) >> 16;
    return (unsigned short)r;
}
__device__ __forceinline__ float bf2f(unsigned short u) {
    union { unsigned int u; float f; } v; v.u = ((unsigned int)u) << 16;
    return v.f;
}
// unpack packed pair (low ushort = even feature, high = odd)
__device__ __forceinline__ float bflo(unsigned int u) {
    union { unsigned int u; float f; } v; v.u = u << 16;
    return v.f;
}
__device__ __forceinline__ float bfhi(unsigned int u) {
    union { unsigned int u; float f; } v; v.u = u & 0xFFFF0000u;
    return v.f;
}

// ---------------- P1a: per-block bucket histograms (dst + src, LDS only) ----------------
// Round-2 lesson: NO global atomicAdd(&deg[src],1) (32 B write-through per op, 68 us).
// Wave-parity dual sub-histograms halve LDS-atomic contention.
__global__ __launch_bounds__(256) void p1a_kernel(const int* __restrict__ src, const int* __restrict__ dst,
                                                  int* __restrict__ mat, int E, int B1, int nbuk) {
    __shared__ int hd[2][NBUK_MAX], hs[2][NBUK_MAX];
    const int t = threadIdx.x;
    const int p = (t >> 6) & 1;   // wave parity
    if (t < nbuk) { hd[0][t] = 0; hd[1][t] = 0; hs[0][t] = 0; hs[1][t] = 0; }
    __syncthreads();
    const int base = blockIdx.x * CH;
    const int cnt = min(CH, E - base);
    for (int k = t; k < cnt; k += 256) {
        int d = dst[base + k];
        int s = src[base + k];
        atomicAdd(&hd[p][d >> 9], 1);
        atomicAdd(&hs[p][s >> 9], 1);
    }
    __syncthreads();
    if (t < nbuk) {
        mat[t * B1 + blockIdx.x] = hd[0][t] + hd[1][t];
        mat[(nbuk + t) * B1 + blockIdx.x] = hs[0][t] + hs[1][t];
    }
}

// ---------------- 3-phase exclusive scan ----------------
__global__ __launch_bounds__(256) void scan1_kernel(const int* __restrict__ cnt,
                                                    int* __restrict__ seg,
                                                    int* __restrict__ bsums, int N) {
    __shared__ int tsum[256];
    const int t = threadIdx.x;
    const int base = blockIdx.x * 1024 + t * 4;
    int v0 = (base + 0 < N) ? cnt[base + 0] : 0;
    int v1 = (base + 1 < N) ? cnt[base + 1] : 0;
    int v2 = (base + 2 < N) ? cnt[base + 2] : 0;
    int v3 = (base + 3 < N) ? cnt[base + 3] : 0;
    tsum[t] = v0 + v1 + v2 + v3;
    __syncthreads();
    for (int off = 1; off < 256; off <<= 1) {
        int x = (t >= off) ? tsum[t - off] : 0;
        __syncthreads();
        if (t >= off) tsum[t] += x;
        __syncthreads();
    }
    int run = (t > 0) ? tsum[t - 1] : 0;
    if (base + 0 < N) seg[base + 0] = run; run += v0;
    if (base + 1 < N) seg[base + 1] = run; run += v1;
    if (base + 2 < N) seg[base + 2] = run; run += v2;
    if (base + 3 < N) seg[base + 3] = run;
    if (t == 255) bsums[blockIdx.x] = tsum[255];
}

__global__ void scan2_kernel(int* __restrict__ bsums, int* __restrict__ seg, int N, int G) {
    __shared__ int s[256];
    int t = threadIdx.x;
    if (t < G) s[t] = bsums[t];
    __syncthreads();
    if (t == 0) {
        int run = 0;
        for (int i = 0; i < G; ++i) { int v = s[i]; s[i] = run; run += v; }
        seg[N] = run;
    }
    __syncthreads();
    if (t < G) bsums[t] = s[t];
}

__global__ __launch_bounds__(256) void scan3_kernel(int* __restrict__ seg,
                                                    const int* __restrict__ bsums, int N) {
    int add = bsums[blockIdx.x];
    int base = blockIdx.x * 1024 + threadIdx.x * 4;
#pragma unroll
    for (int i = 0; i < 4; ++i) {
        int idx = base + i;
        if (idx < N) seg[idx] += add;
    }
}

// ---------------- P1c: LDS-staged partition scatter (both sides) ----------------
// Bucket id recorded at scatter time (bkD uchar for dst side; packed into the
// free high bits of stS for src side) -> writeout has ZERO binary searches.
// Downstream: P2 reads dst entries with (v>>SRC_BITS)&511 and v&0x1FFFF; S2 reads
// src entries with &511 -- the packed bucket bits are invisible to both.
__global__ __launch_bounds__(256) void p1c_kernel(const int* __restrict__ src, const int* __restrict__ dst,
                                                  const int* __restrict__ mat,
                                                  const int* __restrict__ scan,
                                                  int* __restrict__ pedge,
                                                  int E, int B1, int nbuk) {
    __shared__ int hd[NBUK_MAX], hs[NBUK_MAX];
    __shared__ int curD[NBUK_MAX], curS[NBUK_MAX];
    __shared__ int baseD[NBUK_MAX], baseS[NBUK_MAX];
    __shared__ int stD[CH];
    __shared__ int stS[CH];
    __shared__ unsigned char bkD[CH];
    const int t = threadIdx.x;
    if (t < nbuk) {
        hd[t] = mat[t * B1 + blockIdx.x];
        hs[t] = mat[(nbuk + t) * B1 + blockIdx.x];
    }
    const int base = blockIdx.x * CH;
    const int cnt = min(CH, E - base);
    int dl[CH / 256], sl[CH / 256];
#pragma unroll
    for (int k = 0; k < CH / 256; ++k) {
        int i = t + k * 256;
        if (i < cnt) {
            dl[k] = dst[base + i];
            sl[k] = src[base + i];
        }
    }
    __syncthreads();
    for (int off = 1; off < nbuk; off <<= 1) {
        int v0 = (t >= off && t < nbuk) ? hd[t - off] : 0;
        int w0 = (t >= off && t < nbuk) ? hs[t - off] : 0;
        __syncthreads();
        if (t < nbuk) { hd[t] += v0; hs[t] += w0; }
        __syncthreads();
    }
    if (t < nbuk) {
        int excD = t ? hd[t - 1] : 0;
        int excS = t ? hs[t - 1] : 0;
        curD[t] = excD;
        curS[t] = excS;
        baseD[t] = scan[t * B1 + blockIdx.x] - excD;
        baseS[t] = scan[(nbuk + t) * B1 + blockIdx.x] - excS;
    }
    __syncthreads();
#pragma unroll
    for (int k = 0; k < CH / 256; ++k) {
        int i = t + k * 256;
        if (i < cnt) {
            int j = dl[k] >> 9;
            int p = atomicAdd(&curD[j], 1);
            stD[p] = ((dl[k] & 511) << SRC_BITS) | sl[k];
            bkD[p] = (unsigned char)j;
            int jq = sl[k] >> 9;
            int q = atomicAdd(&curS[jq], 1);
            stS[q] = sl[k] | (jq << SRC_BITS);
        }
    }
    __syncthreads();
    for (int i = t; i < cnt; i += 256) {
        int b = bkD[i];
        pedge[baseD[b] + i] = stD[i];
        int v = stS[i];
        pedge[baseS[v >> SRC_BITS] + i] = v;
    }
}

// ---------------- P2+S2 merged: per-bucket sort / histograms ----------------
// blocks [0, nbuk)       : P2 role — local sort -> esrc, seg, norm_dst
// blocks [nbuk, 2*nbuk)  : S2 role — src histogram -> norm_src
__global__ __launch_bounds__(512) void p2s2_kernel(const int* __restrict__ pedge,
                                                   const int* __restrict__ scan,
                                                   int* __restrict__ esrc, int* __restrict__ seg,
                                                   float* __restrict__ norm_dst,
                                                   float* __restrict__ norm_src,
                                                   int N, int E, int B1, int nbuk) {
    __shared__ int h[512];
    __shared__ int cur[512];
    __shared__ int stage[MAXB];
    const int t = threadIdx.x;
    const int b0 = blockIdx.x;
    if (b0 >= nbuk) {
        // ---- S2 role ----
        const int b = b0 - nbuk;
        h[t] = 0;
        __syncthreads();
        const int sb0 = scan[(nbuk + b) * B1];
        const int sb1 = scan[(nbuk + b + 1) * B1];
        for (int i = sb0 + t; i < sb1; i += 512) atomicAdd(&h[pedge[i] & 511], 1);
        __syncthreads();
        int n = (b << 9) + t;
        if (n < N) norm_src[n] = rsqrtf(fmaxf((float)h[t], 1.0f));
        return;
    }
    // ---- P2 role ----
    const int b = b0;
    h[t] = 0;
    __syncthreads();
    const int bb0 = scan[b * B1];
    const int bb1 = scan[(b + 1) * B1];
    for (int i = bb0 + t; i < bb1; i += 512) atomicAdd(&h[(pedge[i] >> SRC_BITS) & 511], 1);
    __syncthreads();
    for (int off = 1; off < 512; off <<= 1) {
        int v = (t >= off) ? h[t - off] : 0;
        __syncthreads();
        h[t] += v;
        __syncthreads();
    }
    {
        int exc = t ? h[t - 1] : 0;
        cur[t] = exc;
        int n = (b << 9) + t;
        if (n < N) {
            seg[n] = bb0 + exc;
            norm_dst[n] = rsqrtf(fmaxf((float)(h[t] - exc), 1.0f));
        }
        if (b == 0 && t == 0) seg[N] = E;
    }
    __syncthreads();
    const int cnt = bb1 - bb0;
    for (int i = bb0 + t; i < bb1; i += 512) {
        int v = pedge[i];
        int j = (v >> SRC_BITS) & 511;
        int p = atomicAdd(&cur[j], 1);
        int s = v & ((1 << SRC_BITS) - 1);
        if (p < MAXB) stage[p] = s; else esrc[bb0 + p] = s;
    }
    __syncthreads();
    for (int i = t; i < cnt && i < MAXB; i += 512) esrc[bb0 + i] = stage[i];
}

// ---------------- X(bf16) = (H @ W) * norm_row  — MFMA split-bf16 ----------------
// Row-major X (128 B/row = one cache line: 8 feature-lanes coalesce to ONE line
// per edge in segsum — round-4 lesson: chunk-split layouts 8x the request count).
// Row N (one past the real nodes) is all-zero: segsum's masked slots redirect to it.
template<int K>
__global__ __launch_bounds__(256) void gemm_norm(const float* __restrict__ H,
                                                 const float* __restrict__ W,
                                                 const float* __restrict__ norm,
                                                 unsigned short* __restrict__ X, int N) {
    constexpr int KP = K + 8;  // padded stride (halves)
    __shared__ __align__(16) unsigned short sHi[64 * KP];
    __shared__ __align__(16) unsigned short sLo[64 * KP];
    const int tid = threadIdx.x;

    // stage W (row-major [K][64]) transposed, split hi/lo
    for (int idx = tid; idx < K * 64; idx += 256) {
        int k = idx >> 6;
        int c = idx & 63;
        float v = W[idx];
        unsigned short hi = f2bf(v);
        sHi[c * KP + k] = hi;
        sLo[c * KP + k] = f2bf(v - bf2f(hi));
    }
    __syncthreads();

    const int w = tid >> 6;
    const int lane = tid & 63;
    const int quad = lane >> 4;
    const int l16 = lane & 15;
    const int n0 = blockIdx.x * 64;
    const int arow = n0 + w * 16 + l16;
    const int arow_c = (arow < N) ? arow : (N - 1);
    const float* Hrow = H + (size_t)arow_c * K + quad * 8;

    f32x4 acc[4];
#pragma unroll
    for (int t = 0; t < 4; ++t) acc[t] = (f32x4){0.0f, 0.0f, 0.0f, 0.0f};

    float4 p0 = *(const float4*)(Hrow + 0);
    float4 p1 = *(const float4*)(Hrow + 4);

#pragma unroll
    for (int kc = 0; kc < K / 32; ++kc) {
        const float v[8] = {p0.x, p0.y, p0.z, p0.w, p1.x, p1.y, p1.z, p1.w};
        bf16x8 aHi, aLo;
#pragma unroll
        for (int j = 0; j < 8; ++j) {
            unsigned short hi = f2bf(v[j]);
            aHi[j] = (short)hi;
            aLo[j] = (short)f2bf(v[j] - bf2f(hi));
        }
        if (kc + 1 < K / 32) {
            p0 = *(const float4*)(Hrow + (kc + 1) * 32 + 0);
            p1 = *(const float4*)(Hrow + (kc + 1) * 32 + 4);
        }
        const int kbase = kc * 32 + quad * 8;
#pragma unroll
        for (int t = 0; t < 4; ++t) {
            const int col = t * 16 + l16;
            const bf16x8 bHi = *(const bf16x8*)&sHi[col * KP + kbase];
            const bf16x8 bLo = *(const bf16x8*)&sLo[col * KP + kbase];
            acc[t] = __builtin_amdgcn_mfma_f32_16x16x32_bf16(aLo, bHi, acc[t], 0, 0, 0);
            acc[t] = __builtin_amdgcn_mfma_f32_16x16x32_bf16(aHi, bLo, acc[t], 0, 0, 0);
            acc[t] = __builtin_amdgcn_mfma_f32_16x16x32_bf16(aHi, bHi, acc[t], 0, 0, 0);
        }
    }

#pragma unroll
    for (int r = 0; r < 4; ++r) {
        const int node = n0 + w * 16 + quad * 4 + r;
        if (node < N) {
            const float s = norm[node];
#pragma unroll
            for (int t = 0; t < 4; ++t) {
                X[(size_t)node * 64 + t * 16 + l16] = f2bf(acc[t][r] * s);
            }
        } else if (node == N) {
            // zero row for segsum's masked-slot redirect
#pragma unroll
            for (int t = 0; t < 4; ++t) {
                X[(size_t)node * 64 + t * 16 + l16] = 0;
            }
        }
    }
}

// ---------------- segment sum over CSR (bf16 X rows) + fused epilogue ----------------
// 1 node per wave (zero divergence). FLAT-32 with VECTOR esrc read: slot eh owns
// 4 consecutive edges loaded as one uint4 (dwordx4) -> 1 index load + 4 independent
// masked-redirect row gathers per pass. deg ~ Poisson(16): one pass covers ~all nodes.
// Out-of-range slots gather the L1-hot zero row X[N].
// Epilogue: 3-stage reduce-scatter -> each lane owns one feature -> coalesced store.
template<bool ELU>
__global__ __launch_bounds__(256) void segsum_kernel(const unsigned short* __restrict__ X,
                                                     const int* __restrict__ esrc,
                                                     const int* __restrict__ seg,
                                                     const float* __restrict__ norm_dst,
                                                     const float* __restrict__ bias,
                                                     float* __restrict__ out, int N) {
    const int node = __builtin_amdgcn_readfirstlane(blockIdx.x * 4 + (threadIdx.x >> 6));
    if (node >= N) return;
    const int lane = threadIdx.x & 63;
    const int eh = lane >> 3;          // edge slot 0..7 (owns 4 consecutive edges)
    const int fl = lane & 7;           // feature group (8 bf16 = 16 B)
    const unsigned flo = (unsigned)fl << 4;
    // feature this lane will own after reduce-scatter (bit-reversed eh)
    const int fown = fl * 8 + ((eh & 1) << 2) + (eh & 2) + (eh >> 2);
    const float bv = bias[fown];
    const int s0 = seg[node];
    const int s1 = seg[node + 1];
    const char* Xb = (const char*)X;
    f32x2 A0 = {0.0f, 0.0f}, A1 = {0.0f, 0.0f}, A2 = {0.0f, 0.0f}, A3 = {0.0f, 0.0f};
#define ACC8(u) \
    A0 += (f32x2){bflo(u.x), bfhi(u.x)}; A1 += (f32x2){bflo(u.y), bfhi(u.y)}; \
    A2 += (f32x2){bflo(u.z), bfhi(u.z)}; A3 += (f32x2){bflo(u.w), bfhi(u.w)};
    int e = s0;
    while (true) {
        const int b4 = e + eh * 4;
        const uint4 q = *(const uint4*)&esrc[b4];   // 4B-aligned dwordx4; esrc padded
        const int r0 = (b4 + 0 < s1) ? (int)q.x : N;
        const int r1 = (b4 + 1 < s1) ? (int)q.y : N;
        const int r2 = (b4 + 2 < s1) ? (int)q.z : N;
        const int r3 = (b4 + 3 < s1) ? (int)q.w : N;
        const uint4 u0 = *(const uint4*)(Xb + ((((unsigned)r0) << 7) | flo));
        const uint4 u1 = *(const uint4*)(Xb + ((((unsigned)r1) << 7) | flo));
        const uint4 u2 = *(const uint4*)(Xb + ((((unsigned)r2) << 7) | flo));
        const uint4 u3 = *(const uint4*)(Xb + ((((unsigned)r3) << 7) | flo));
        ACC8(u0);
        ACC8(u1);
        ACC8(u2);
        ACC8(u3);
        e += 32;
        if (e >= s1) break;
    }
#undef ACC8
    // reduce-scatter across the 8 slots: 3 stages, each lane keeps a shrinking set
    float a0 = A0.x, a1 = A0.y, a2 = A1.x, a3 = A1.y;
    float a4 = A2.x, a5 = A2.y, a6 = A3.x, a7 = A3.y;
    const bool p0 = (eh & 1) != 0;
    const bool p1 = (eh & 2) != 0;
    const bool p2 = (eh & 4) != 0;
    float t0, t1, t2, t3;
    {
        float sA = p0 ? a0 : a4, kA = p0 ? a4 : a0;
        float sB = p0 ? a1 : a5, kB = p0 ? a5 : a1;
        float sC = p0 ? a2 : a6, kC = p0 ? a6 : a2;
        float sD = p0 ? a3 : a7, kD = p0 ? a7 : a3;
        t0 = kA + __shfl_xor(sA, 8);
        t1 = kB + __shfl_xor(sB, 8);
        t2 = kC + __shfl_xor(sC, 8);
        t3 = kD + __shfl_xor(sD, 8);
    }
    float u0, u1;
    {
        float sA = p1 ? t0 : t2, kA = p1 ? t2 : t0;
        float sB = p1 ? t1 : t3, kB = p1 ? t3 : t1;
        u0 = kA + __shfl_xor(sA, 16);
        u1 = kB + __shfl_xor(sB, 16);
    }
    float v;
    {
        float sA = p2 ? u0 : u1, kA = p2 ? u1 : u0;
        v = kA + __shfl_xor(sA, 32);
    }
    // epilogue: every lane handles exactly one feature
    const float s = norm_dst[node];
    float r = v * s + bv;
    if (ELU) r = r > 0.0f ? r : expm1f(r);
    out[(size_t)node * 64 + fown] = r;
}

extern "C" void kernel_launch(void* const* d_in, const int* in_sizes, int n_in,
                              void* d_out, int out_size, void* d_ws, size_t ws_size,
                              hipStream_t stream) {
    const float* h   = (const float*)d_in[0];
    const int*   src = (const int*)d_in[1];
    const int*   dst = (const int*)d_in[2];
    const float* W1  = (const float*)d_in[3];
    const float* b1  = (const float*)d_in[4];
    const float* W2  = (const float*)d_in[5];
    const float* b2  = (const float*)d_in[6];
    float* out = (float*)d_out;

    const int N = in_sizes[0] / 128;       // 100000
    const int E = in_sizes[1];             // 1600000
    const int nbuk = (N + 511) >> 9;       // 196
    const int B1 = (E + CH - 1) / CH;      // 391
    const int M = 2 * nbuk * B1;

    int* iw = (int*)d_ws;
    int* mat   = iw;                       // M
    int* scanb = mat + M;                  // M+4
    int* bsums = scanb + M + 4;            // 256
    int* pedge = bsums + 256;              // 2E
    int* esrc  = pedge + 2 * (size_t)E;    // E (+40 pad for flat-32 over-read)
    int* seg   = esrc + (size_t)E + 40;    // N+1 (+pad)
    uintptr_t fp = (uintptr_t)(seg + (size_t)N + 4);
    fp = (fp + 63) & ~(uintptr_t)63;
    float* norm_src = (float*)fp;                      // N
    float* norm_dst = norm_src + (size_t)N;            // N
    float* H1       = norm_dst + (size_t)N;            // 64N floats
    unsigned short* Xb = (unsigned short*)(H1 + 64 * (size_t)N);  // 64(N+1) bf16

    // ---- CSR build ----
    p1a_kernel<<<B1, 256, 0, stream>>>(src, dst, mat, E, B1, nbuk);
    const int G = (M + 1023) / 1024;
    scan1_kernel<<<G, 256, 0, stream>>>(mat, scanb, bsums, M);
    scan2_kernel<<<1, 256, 0, stream>>>(bsums, scanb, M, G);
    scan3_kernel<<<G, 256, 0, stream>>>(scanb, bsums, M);
    p1c_kernel<<<B1, 256, 0, stream>>>(src, dst, mat, scanb, pedge, E, B1, nbuk);
    p2s2_kernel<<<2 * nbuk, 512, 0, stream>>>(pedge, scanb, esrc, seg, norm_dst, norm_src,
                                              N, E, B1, nbuk);

    const int segGrid = (N + 3) / 4;
    const int gemmGrid = (N + 64) / 64;    // +1 so the zero row (node==N) is always written

    // ---- layer 1 ----
    gemm_norm<128><<<gemmGrid, 256, 0, stream>>>(h, W1, norm_src, Xb, N);
    segsum_kernel<true><<<segGrid, 256, 0, stream>>>(Xb, esrc, seg, norm_dst, b1, H1, N);

    // ---- layer 2 ----
    gemm_norm<64><<<gemmGrid, 256, 0, stream>>>(H1, W2, norm_src, Xb, N);
    segsum_kernel<false><<<segGrid, 256, 0, stream>>>(Xb, esrc, seg, norm_dst, b2, out, N);
}